// Round 2
// baseline (365.595 us; speedup 1.0000x reference)
//
#include <hip/hip_runtime.h>
#include <hip/hip_bf16.h>

// InvertAffine: input trf (B, 3, 4) fp32 "affine shift" matrices.
// out = inv([[I3+T, t],[0,1]])[:3,:] = [A^-1, -A^-1 t], A = I3 + T[:, :, :3].
// Closed-form 3x3 adjugate inverse (A = I + 0.1*N -> det ~ 1, well-conditioned).
//
// Memory-bound: 201 MB in + 201 MB out -> ~64 us floor at 6.3 TB/s.
// R1 was 339 us: lane-stride-48B float4 access = 3x TA transactions per load/
// store instruction. Fix: LDS tile staging so ALL global traffic is unit-stride
// coalesced float4; per-thread matrix gathers come from LDS.
// LDS bank note: ds_read_b128 at 48B stride -> bank-group 3t mod 8 (bijection
// mod 8) -> uniform 8 lanes/group = conflict-free minimum for b128. No pad.

constexpr int BLOCK = 256;
constexpr int MPB = 256;  // matrices per tile (12 KB LDS)

__global__ __launch_bounds__(BLOCK) void InvertAffine_kernel(
    const float4* __restrict__ in, float4* __restrict__ out, int n) {
    __shared__ float4 lds[MPB * 3];
    const int t = threadIdx.x;
    const int ntiles = (n + MPB - 1) / MPB;

    for (int tile = blockIdx.x; tile < ntiles; tile += gridDim.x) {
        const int mbase = tile * MPB;
        const int f4base = mbase * 3;
        const int nm = min(MPB, n - mbase);  // matrices in this tile
        const int nf4 = nm * 3;

        // ---- coalesced global -> regs -> LDS (3 x unit-stride float4) ----
        float4 v[3];
        #pragma unroll
        for (int k = 0; k < 3; ++k) {
            int idx = t + k * BLOCK;
            if (idx < nf4) v[k] = in[f4base + idx];
        }
        #pragma unroll
        for (int k = 0; k < 3; ++k) {
            int idx = t + k * BLOCK;
            if (idx < nf4) lds[idx] = v[k];
        }
        __syncthreads();

        // ---- per-thread matrix from LDS, compute inverse ----
        float4 q0, q1, q2;
        const bool act = (t < nm);
        if (act) {
            float4 r0 = lds[t * 3 + 0];
            float4 r1 = lds[t * 3 + 1];
            float4 r2 = lds[t * 3 + 2];

            float a00 = 1.0f + r0.x, a01 = r0.y,        a02 = r0.z,        t0 = r0.w;
            float a10 = r1.x,        a11 = 1.0f + r1.y, a12 = r1.z,        t1 = r1.w;
            float a20 = r2.x,        a21 = r2.y,        a22 = 1.0f + r2.z, t2 = r2.w;

            float c00 = a11 * a22 - a12 * a21;
            float c01 = a12 * a20 - a10 * a22;
            float c02 = a10 * a21 - a11 * a20;
            float det = a00 * c00 + a01 * c01 + a02 * c02;
            float rdet = 1.0f / det;

            float i00 = c00 * rdet;
            float i01 = (a02 * a21 - a01 * a22) * rdet;
            float i02 = (a01 * a12 - a02 * a11) * rdet;
            float i10 = c01 * rdet;
            float i11 = (a00 * a22 - a02 * a20) * rdet;
            float i12 = (a02 * a10 - a00 * a12) * rdet;
            float i20 = c02 * rdet;
            float i21 = (a01 * a20 - a00 * a21) * rdet;
            float i22 = (a00 * a11 - a01 * a10) * rdet;

            float o0 = -(i00 * t0 + i01 * t1 + i02 * t2);
            float o1 = -(i10 * t0 + i11 * t1 + i12 * t2);
            float o2 = -(i20 * t0 + i21 * t1 + i22 * t2);

            q0 = make_float4(i00, i01, i02, o0);
            q1 = make_float4(i10, i11, i12, o1);
            q2 = make_float4(i20, i21, i22, o2);
        }
        __syncthreads();  // all LDS reads done before overwrite

        if (act) {
            lds[t * 3 + 0] = q0;
            lds[t * 3 + 1] = q1;
            lds[t * 3 + 2] = q2;
        }
        __syncthreads();

        // ---- coalesced LDS -> global (3 x unit-stride float4) ----
        #pragma unroll
        for (int k = 0; k < 3; ++k) {
            int idx = t + k * BLOCK;
            if (idx < nf4) out[f4base + idx] = lds[idx];
        }
        __syncthreads();  // buffer reused next tile
    }
}

extern "C" void kernel_launch(void* const* d_in, const int* in_sizes, int n_in,
                              void* d_out, int out_size, void* d_ws, size_t ws_size,
                              hipStream_t stream) {
    const float4* in = (const float4*)d_in[0];
    float4* out = (float4*)d_out;
    int n = in_sizes[0] / 12;  // number of (3,4) matrices

    int ntiles = (n + MPB - 1) / MPB;
    int blocks = ntiles < 2048 ? ntiles : 2048;  // 256 CU x 8 blocks/CU
    InvertAffine_kernel<<<blocks, BLOCK, 0, stream>>>(in, out, n);
}

// Round 3
// 337.423 us; speedup vs baseline: 1.0835x; 1.0835x over previous
//
#include <hip/hip_runtime.h>
#include <hip/hip_bf16.h>

// InvertAffine: input trf (B, 3, 4) fp32 "affine shift" matrices.
// out = inv([[I3+T, t],[0,1]])[:3,:] = [A^-1, -A^-1 t], A = I3 + T[:, :, :3].
// Closed-form 3x3 adjugate inverse (A = I + 0.1*N -> det ~ 1, well-conditioned).
//
// R1 (direct, strided float4): kernel <= 121 us. R2 (LDS-staged): 137.5 us —
// LDS round-trip + 4 barriers/tile was a net LOSS; 48B-lane-stride global
// access is byte-ideal anyway (each wave's 3 dwordx4 ops fully consume all
// touched 64B lines). R2 counters: FETCH 183 MB (~ideal), WRITE 388 MB (~2x,
// suspected parasitic poison-fill drain / restore overlap, not our stores).
//
// R3: leanest structure. Direct loads, nontemporal load+store (read-once /
// write-once streaming), no grid-stride loop (n = 16384*256 exactly; guard
// kept for safety), one matrix per thread, full grid.

typedef float f4v __attribute__((ext_vector_type(4)));

__global__ __launch_bounds__(256) void InvertAffine_kernel(
    const f4v* __restrict__ in, f4v* __restrict__ out, int n) {
    int i = blockIdx.x * 256 + threadIdx.x;
    if (i >= n) return;

    f4v r0 = __builtin_nontemporal_load(&in[i * 3 + 0]);
    f4v r1 = __builtin_nontemporal_load(&in[i * 3 + 1]);
    f4v r2 = __builtin_nontemporal_load(&in[i * 3 + 2]);

    float a00 = 1.0f + r0.x, a01 = r0.y,        a02 = r0.z,        t0 = r0.w;
    float a10 = r1.x,        a11 = 1.0f + r1.y, a12 = r1.z,        t1 = r1.w;
    float a20 = r2.x,        a21 = r2.y,        a22 = 1.0f + r2.z, t2 = r2.w;

    // Adjugate (cofactor) inverse of A
    float c00 = a11 * a22 - a12 * a21;
    float c01 = a12 * a20 - a10 * a22;
    float c02 = a10 * a21 - a11 * a20;
    float det = a00 * c00 + a01 * c01 + a02 * c02;
    float rdet = 1.0f / det;

    float i00 = c00 * rdet;
    float i01 = (a02 * a21 - a01 * a22) * rdet;
    float i02 = (a01 * a12 - a02 * a11) * rdet;
    float i10 = c01 * rdet;
    float i11 = (a00 * a22 - a02 * a20) * rdet;
    float i12 = (a02 * a10 - a00 * a12) * rdet;
    float i20 = c02 * rdet;
    float i21 = (a01 * a20 - a00 * a21) * rdet;
    float i22 = (a00 * a11 - a01 * a10) * rdet;

    // Translation column: -A^-1 * t
    float o0 = -(i00 * t0 + i01 * t1 + i02 * t2);
    float o1 = -(i10 * t0 + i11 * t1 + i12 * t2);
    float o2 = -(i20 * t0 + i21 * t1 + i22 * t2);

    f4v q0 = {i00, i01, i02, o0};
    f4v q1 = {i10, i11, i12, o1};
    f4v q2 = {i20, i21, i22, o2};
    __builtin_nontemporal_store(q0, &out[i * 3 + 0]);
    __builtin_nontemporal_store(q1, &out[i * 3 + 1]);
    __builtin_nontemporal_store(q2, &out[i * 3 + 2]);
}

extern "C" void kernel_launch(void* const* d_in, const int* in_sizes, int n_in,
                              void* d_out, int out_size, void* d_ws, size_t ws_size,
                              hipStream_t stream) {
    const f4v* in = (const f4v*)d_in[0];
    f4v* out = (f4v*)d_out;
    int n = in_sizes[0] / 12;  // number of (3,4) matrices

    int blocks = (n + 255) / 256;  // 16384 for B = 4,194,304 — no loop needed
    InvertAffine_kernel<<<blocks, 256, 0, stream>>>(in, out, n);
}